// Round 6
// baseline (854.343 us; speedup 1.0000x reference)
//
#include <hip/hip_runtime.h>
#include <math.h>

namespace {
constexpr int NB = 256;   // batch
constexpr int NR = 1152;  // routes
constexpr int NC = 10;    // output capsules
constexpr int NO = 16;    // output dim
constexpr int NI = 8;     // input dim
}

// b = 0, c = 1/R  (softmax of zeros over R)
__global__ __launch_bounds__(256) void k_init(float* __restrict__ bbuf,
                                              float* __restrict__ cbuf) {
    int i = blockIdx.x * 256 + threadIdx.x;
    if (i < NR * NC) { bbuf[i] = 0.0f; cbuf[i] = 1.0f / NR; }
}

// xT[r][b][i] = x[b][r][i], LDS-staged
__global__ __launch_bounds__(256) void k_transpose(const float* __restrict__ x,
                                                   float* __restrict__ xT) {
    __shared__ __align__(16) float t[8][1028];
    const int rb = blockIdx.x;     // 9 tiles of 128 r
    const int bb = blockIdx.y;     // 32 tiles of 8 b
    #pragma unroll
    for (int k = 0; k < 8; ++k) {
        const float4* src = reinterpret_cast<const float4*>(
            x + ((size_t)(bb * 8 + k) * NR + rb * 128) * NI);
        *reinterpret_cast<float4*>(&t[k][threadIdx.x * 4]) = src[threadIdx.x];
    }
    __syncthreads();
    #pragma unroll
    for (int it = 0; it < 8; ++it) {
        int f  = it * 256 + threadIdx.x;
        int i4 = f & 1;
        int b  = (f >> 1) & 7;
        int r  = f >> 4;
        float4 v = *reinterpret_cast<float4*>(&t[b][r * 8 + i4 * 4]);
        *reinterpret_cast<float4*>(
            xT + ((size_t)(rb * 128 + r) * NB + bb * 8 + b) * NI + i4 * 4) = v;
    }
}

// part chunk p(c,ch2,b,o) = sum over 2*RCHW r's of c[r,c] * (W[r,c,o,:].x[b,r,:])
// Block=(ch2,c), 4 waves = (rs, bh); lane owns b = bh*128+lane and b+64, all 16 o.
// W broadcast from LDS (uniform addr, conflict-free); c[r,c] folded into x.
template <int NCH2, int RCHW>
__global__ __launch_bounds__(256, 4) void k_partial(const float* __restrict__ xT,
                                                    const float* __restrict__ W,
                                                    const float* __restrict__ cbuf,
                                                    float4* __restrict__ part) {
    const int ch2  = blockIdx.x;
    const int c    = blockIdx.y;
    const int tid  = threadIdx.x;
    const int wave = tid >> 6, lane = tid & 63;
    const int rs = wave >> 1, bh = wave & 1;

    __shared__ __align__(16) float Wl[2 * RCHW * 128];
    __shared__ __align__(16) float mrg[2][64][2 * NO];   // 16 KB

    for (int idx = tid; idx < 2 * RCHW * 32; idx += 256) {
        int rr = idx >> 5, j = idx & 31;
        reinterpret_cast<float4*>(Wl)[idx] =
            *(reinterpret_cast<const float4*>(
                  W + ((size_t)(ch2 * 2 * RCHW + rr) * NC + c) * 128) + j);
    }
    __syncthreads();

    float acc0[NO] = {}, acc1[NO] = {};
    const float* xb = xT + (((size_t)(ch2 * 2 + rs) * RCHW) * NB + bh * 128 + lane) * NI;
    const int rbase = (ch2 * 2 + rs) * RCHW;

    #pragma unroll
    for (int rr = 0; rr < RCHW; ++rr) {
        const float cr = cbuf[(size_t)(rbase + rr) * NC + c];   // uniform -> s_load
        const float4* xp = reinterpret_cast<const float4*>(xb + (size_t)rr * NB * NI);
        float4 xa0 = xp[0],   xa1 = xp[1];     // b
        float4 xb0 = xp[128], xb1 = xp[129];   // b + 64
        xa0.x *= cr; xa0.y *= cr; xa0.z *= cr; xa0.w *= cr;
        xa1.x *= cr; xa1.y *= cr; xa1.z *= cr; xa1.w *= cr;
        xb0.x *= cr; xb0.y *= cr; xb0.z *= cr; xb0.w *= cr;
        xb1.x *= cr; xb1.y *= cr; xb1.z *= cr; xb1.w *= cr;
        const float* wrow = &Wl[(rs * RCHW + rr) * 128];
        #pragma unroll
        for (int o = 0; o < NO; ++o) {
            float4 w0 = *reinterpret_cast<const float4*>(wrow + o * 8);
            float4 w1 = *reinterpret_cast<const float4*>(wrow + o * 8 + 4);
            acc0[o] += w0.x*xa0.x + w0.y*xa0.y + w0.z*xa0.z + w0.w*xa0.w
                     + w1.x*xa1.x + w1.y*xa1.y + w1.z*xa1.z + w1.w*xa1.w;
            acc1[o] += w0.x*xb0.x + w0.y*xb0.y + w0.z*xb0.z + w0.w*xb0.w
                     + w1.x*xb1.x + w1.y*xb1.y + w1.z*xb1.z + w1.w*xb1.w;
        }
    }

    __syncthreads();
    if (rs == 1) {
        #pragma unroll
        for (int o = 0; o < NO; ++o) {
            mrg[bh][lane][o]      = acc0[o];
            mrg[bh][lane][NO + o] = acc1[o];
        }
    }
    __syncthreads();
    if (rs == 0) {
        #pragma unroll
        for (int o = 0; o < NO; ++o) {
            acc0[o] += mrg[bh][lane][o];
            acc1[o] += mrg[bh][lane][NO + o];
        }
        int b0 = bh * 128 + lane;
        float4* p0 = part + (((size_t)c * NCH2 + ch2) * NB + b0) * 4;
        float4* p1 = p0 + 64 * 4;
        #pragma unroll
        for (int q = 0; q < 4; ++q) {
            p0[q] = make_float4(acc0[q*4+0], acc0[q*4+1], acc0[q*4+2], acc0[q*4+3]);
            p1[q] = make_float4(acc1[q*4+0], acc1[q*4+1], acc1[q*4+2], acc1[q*4+3]);
        }
    }
}

// stage1: sum 8 chunks -> part2[t][e]; t = ((c*NB+b)*4+q), e in [0,E)
__global__ __launch_bounds__(256) void k_reduce1(const float4* __restrict__ part,
                                                 float4* __restrict__ part2,
                                                 int nch2, int E) {
    int t = blockIdx.x * 256 + threadIdx.x;   // [0, 10240)
    int e = blockIdx.y;                        // [0, E)
    int q = t & 3;
    int b = (t >> 2) & 255;
    int c = t >> 10;
    float4 s = make_float4(0.f, 0.f, 0.f, 0.f);
    #pragma unroll
    for (int k = 0; k < 8; ++k) {
        float4 v = part[(((size_t)c * nch2 + e * 8 + k) * NB + b) * 4 + q];
        s.x += v.x; s.y += v.y; s.z += v.z; s.w += v.w;
    }
    part2[(size_t)t * E + e] = s;
}

// stage2: sum E partials, squash, write vbuf[c][b][o] (or out[b][c][o] last)
__global__ __launch_bounds__(256) void k_reduce2(const float4* __restrict__ part2,
                                                 float4* __restrict__ vbuf,
                                                 float4* __restrict__ out,
                                                 int E, int final_pass) {
    int t = blockIdx.x * 256 + threadIdx.x;   // [0, 10240)
    int q = t & 3;
    int b = (t >> 2) & 255;
    int c = t >> 10;
    float4 s = make_float4(0.f, 0.f, 0.f, 0.f);
    for (int e = 0; e < E; ++e) {
        float4 v = part2[(size_t)t * E + e];
        s.x += v.x; s.y += v.y; s.z += v.z; s.w += v.w;
    }
    float4 r;
    r.x = s.x * fabsf(s.x) / (1.0f + s.x * s.x);
    r.y = s.y * fabsf(s.y) / (1.0f + s.y * s.y);
    r.z = s.z * fabsf(s.z) / (1.0f + s.z * s.z);
    r.w = s.w * fabsf(s.w) / (1.0f + s.w * s.w);
    if (final_pass) {
        out[((size_t)b * NC + c) * 4 + q] = r;
    } else {
        vbuf[t] = r;
    }
}

// bbuf[r,c] += (1/B) sum_b sum_o (sum_i W[r,c,o,i] x[b,r,i]) v[c,b,o]
template <int NCH2, int RCHW>
__global__ __launch_bounds__(256, 4) void k_agree(const float* __restrict__ xT,
                                                  const float* __restrict__ W,
                                                  const float* __restrict__ vbuf,
                                                  float* __restrict__ bbuf) {
    const int ch2  = blockIdx.x;
    const int c    = blockIdx.y;
    const int tid  = threadIdx.x;
    const int wave = tid >> 6, lane = tid & 63;
    const int rs = wave >> 1, bh = wave & 1;

    __shared__ __align__(16) float Wl[2 * RCHW * 128];
    __shared__ __align__(16) float plds[2 * RCHW][2][64];

    for (int idx = tid; idx < 2 * RCHW * 32; idx += 256) {
        int rr = idx >> 5, j = idx & 31;
        reinterpret_cast<float4*>(Wl)[idx] =
            *(reinterpret_cast<const float4*>(
                  W + ((size_t)(ch2 * 2 * RCHW + rr) * NC + c) * 128) + j);
    }
    __syncthreads();

    const int b0 = bh * 128 + lane;
    float4 v0[4], v1[4];
    {
        const float4* vp0 = reinterpret_cast<const float4*>(
            vbuf + ((size_t)c * NB + b0) * NO);
        const float4* vp1 = reinterpret_cast<const float4*>(
            vbuf + ((size_t)c * NB + b0 + 64) * NO);
        #pragma unroll
        for (int q = 0; q < 4; ++q) { v0[q] = vp0[q]; v1[q] = vp1[q]; }
    }

    const float* xb = xT + (((size_t)(ch2 * 2 + rs) * RCHW) * NB + b0) * NI;

    #pragma unroll
    for (int rr = 0; rr < RCHW; ++rr) {
        const float4* xp = reinterpret_cast<const float4*>(xb + (size_t)rr * NB * NI);
        float4 xa0 = xp[0],   xa1 = xp[1];
        float4 xb0 = xp[128], xb1 = xp[129];
        const float* wrow = &Wl[(rs * RCHW + rr) * 128];
        float p = 0.0f;
        #pragma unroll
        for (int o = 0; o < NO; ++o) {
            float4 w0 = *reinterpret_cast<const float4*>(wrow + o * 8);
            float4 w1 = *reinterpret_cast<const float4*>(wrow + o * 8 + 4);
            float d0 = w0.x*xa0.x + w0.y*xa0.y + w0.z*xa0.z + w0.w*xa0.w
                     + w1.x*xa1.x + w1.y*xa1.y + w1.z*xa1.z + w1.w*xa1.w;
            float d1 = w0.x*xb0.x + w0.y*xb0.y + w0.z*xb0.z + w0.w*xb0.w
                     + w1.x*xb1.x + w1.y*xb1.y + w1.z*xb1.z + w1.w*xb1.w;
            const float* vf0 = reinterpret_cast<const float*>(&v0[o >> 2]);
            const float* vf1 = reinterpret_cast<const float*>(&v1[o >> 2]);
            p += d0 * vf0[o & 3] + d1 * vf1[o & 3];
        }
        plds[rs * RCHW + rr][bh][lane] = p;
    }
    __syncthreads();

    for (int r = wave; r < 2 * RCHW; r += 4) {
        float s = plds[r][0][lane] + plds[r][1][lane];
        s += __shfl_xor(s, 1);
        s += __shfl_xor(s, 2);
        s += __shfl_xor(s, 4);
        s += __shfl_xor(s, 8);
        s += __shfl_xor(s, 16);
        s += __shfl_xor(s, 32);
        if (lane == 0)
            bbuf[((size_t)ch2 * 2 * RCHW + r) * NC + c] += s * (1.0f / NB);
    }
}

// softmax over r (axis 0) per column c
__global__ __launch_bounds__(256) void k_softmax(const float* __restrict__ bbuf,
                                                 float* __restrict__ cbuf) {
    const int c   = blockIdx.x;
    const int tid = threadIdx.x;
    __shared__ float sred[4];
    __shared__ float sred2[4];
    int wave = tid >> 6, lane = tid & 63;

    float m = -1e30f;
    for (int r = tid; r < NR; r += 256) m = fmaxf(m, bbuf[r * NC + c]);
    #pragma unroll
    for (int off = 1; off < 64; off <<= 1) m = fmaxf(m, __shfl_xor(m, off));
    if (lane == 0) sred[wave] = m;
    __syncthreads();
    m = fmaxf(fmaxf(sred[0], sred[1]), fmaxf(sred[2], sred[3]));

    float s = 0.0f;
    for (int r = tid; r < NR; r += 256) {
        float e = expf(bbuf[r * NC + c] - m);
        cbuf[r * NC + c] = e;
        s += e;
    }
    #pragma unroll
    for (int off = 1; off < 64; off <<= 1) s += __shfl_xor(s, off);
    if (lane == 0) sred2[wave] = s;
    __syncthreads();
    s = sred2[0] + sred2[1] + sred2[2] + sred2[3];
    float inv = 1.0f / s;
    for (int r = tid; r < NR; r += 256) cbuf[r * NC + c] *= inv;
}

extern "C" void kernel_launch(void* const* d_in, const int* in_sizes, int n_in,
                              void* d_out, int out_size, void* d_ws, size_t ws_size,
                              hipStream_t stream) {
    const float* x = (const float*)d_in[0];   // [256,1152,8]
    const float* W = (const float*)d_in[1];   // [1152,10,16,8]
    float4* out = (float4*)d_out;             // [256,10,16,1]

    // ws need: part + part2 + xT + bbuf + cbuf + vbuf  (NO Wp buffer)
    auto need_bytes = [](int nch2) -> size_t {
        return sizeof(float) * ((size_t)NC * nch2 * NB * NO +        // part
                                (size_t)10240 * (nch2 / 8) * 4 +     // part2
                                (size_t)NR * NB * NI +               // xT
                                2 * (size_t)NR * NC +                // bbuf,cbuf
                                (size_t)NC * NB * NO);               // vbuf
    };
    const int nch2 = (ws_size >= need_bytes(64)) ? 64 : 32;   // 64: 21.49 MB (round-4 proven fit)
    const int E = nch2 / 8;

    float4* part  = (float4*)d_ws;                       // NC*nch2*NB*4 f4
    float4* part2 = part + (size_t)NC * nch2 * NB * 4;   // 10240*E f4
    float*  xT    = (float*)(part2 + (size_t)10240 * E); // NR*NB*NI
    float*  bbuf  = xT + (size_t)NR * NB * NI;
    float*  cbuf  = bbuf + (size_t)NR * NC;
    float*  vbuf  = cbuf + (size_t)NR * NC;

    k_init<<<(NR * NC + 255) / 256, 256, 0, stream>>>(bbuf, cbuf);
    {
        dim3 gt(NR / 128, NB / 8);
        k_transpose<<<gt, 256, 0, stream>>>(x, xT);
    }

    dim3 ghot(nch2, NC);   // c-blocks sharing x are nch2 (mult of 8) apart -> same XCD
    dim3 gr1(40, E);

    for (int it = 0; it < 3; ++it) {
        if (nch2 == 64)
            k_partial<64, 9><<<ghot, 256, 0, stream>>>(xT, W, cbuf, part);
        else
            k_partial<32, 18><<<ghot, 256, 0, stream>>>(xT, W, cbuf, part);

        k_reduce1<<<gr1, 256, 0, stream>>>(part, part2, nch2, E);
        k_reduce2<<<40, 256, 0, stream>>>(part2, (float4*)vbuf, out, E, it == 2 ? 1 : 0);

        if (it < 2) {
            if (nch2 == 64)
                k_agree<64, 9><<<ghot, 256, 0, stream>>>(xT, W, vbuf, bbuf);
            else
                k_agree<32, 18><<<ghot, 256, 0, stream>>>(xT, W, vbuf, bbuf);
            k_softmax<<<NC, 256, 0, stream>>>(bbuf, cbuf);
        }
    }
}

// Round 7
// 161.742 us; speedup vs baseline: 5.2821x; 5.2821x over previous
//
#include <hip/hip_runtime.h>
#include <math.h>

namespace {
constexpr int NB = 256;   // batch
constexpr int NR = 1152;  // routes
constexpr int NC = 10;    // output capsules
constexpr int NO = 16;    // output dim
constexpr int NI = 8;     // input dim
constexpr int NCH2 = 64;  // part slots (proven 21.49 MB ws footprint)
constexpr int RCHP = 18;  // r per k_partial block (64*18 = 1152)
}

// b = 0, c = 1/R  (softmax of zeros over R)
__global__ __launch_bounds__(256) void k_init(float* __restrict__ bbuf,
                                              float* __restrict__ cbuf) {
    int i = blockIdx.x * 256 + threadIdx.x;
    if (i < NR * NC) { bbuf[i] = 0.0f; cbuf[i] = 1.0f / NR; }
}

// xT[r][b][i] = x[b][r][i], LDS-staged
__global__ __launch_bounds__(256) void k_transpose(const float* __restrict__ x,
                                                   float* __restrict__ xT) {
    __shared__ __align__(16) float t[8][1028];
    const int rb = blockIdx.x;     // 9 tiles of 128 r
    const int bb = blockIdx.y;     // 32 tiles of 8 b
    #pragma unroll
    for (int k = 0; k < 8; ++k) {
        const float4* src = reinterpret_cast<const float4*>(
            x + ((size_t)(bb * 8 + k) * NR + rb * 128) * NI);
        *reinterpret_cast<float4*>(&t[k][threadIdx.x * 4]) = src[threadIdx.x];
    }
    __syncthreads();
    #pragma unroll
    for (int it = 0; it < 8; ++it) {
        int f  = it * 256 + threadIdx.x;
        int i4 = f & 1;
        int b  = (f >> 1) & 7;
        int r  = f >> 4;
        float4 v = *reinterpret_cast<float4*>(&t[b][r * 8 + i4 * 4]);
        *reinterpret_cast<float4*>(
            xT + ((size_t)(rb * 128 + r) * NB + bb * 8 + b) * NI + i4 * 4) = v;
    }
}

// part slot p(c,ch,b,o) = sum over RCHP r's of c[r,c] * (W[r,c,o,:].x[b,r,:])
// ROUND-1 PROVEN STRUCTURE: lane = b (256 b per block), o fully unrolled,
// r-loop ROLLED, W (c-folded) broadcast from LDS. acc[16] only.
__global__ __launch_bounds__(256, 2) void k_partial(const float* __restrict__ xT,
                                                    const float* __restrict__ W,
                                                    const float* __restrict__ cbuf,
                                                    float4* __restrict__ part) {
    const int ch = blockIdx.x;     // 0..63
    const int c  = blockIdx.y;     // 0..9
    const int r0 = ch * RCHP;
    const int b  = threadIdx.x;

    __shared__ __align__(16) float Ws[RCHP * 128];   // 9.2 KB, c-scaled

    for (int idx = threadIdx.x; idx < RCHP * 128; idx += 256) {
        int rr = idx >> 7;
        int j  = idx & 127;
        int r  = r0 + rr;
        Ws[idx] = cbuf[r * NC + c] * W[((size_t)r * NC + c) * 128 + j];
    }
    __syncthreads();

    float acc[NO];
    #pragma unroll
    for (int o = 0; o < NO; ++o) acc[o] = 0.0f;

    for (int rr = 0; rr < RCHP; ++rr) {          // rolled: keeps liveness tiny
        const float4* xp = reinterpret_cast<const float4*>(
            xT + ((size_t)(r0 + rr) * NB + b) * NI);
        float4 xa = xp[0];
        float4 xb2 = xp[1];
        const float* wrow = &Ws[rr * 128];
        #pragma unroll
        for (int o = 0; o < NO; ++o) {
            float4 w0 = *reinterpret_cast<const float4*>(wrow + o * 8);
            float4 w1 = *reinterpret_cast<const float4*>(wrow + o * 8 + 4);
            acc[o] += w0.x * xa.x + w0.y * xa.y + w0.z * xa.z + w0.w * xa.w
                    + w1.x * xb2.x + w1.y * xb2.y + w1.z * xb2.z + w1.w * xb2.w;
        }
    }

    float4* pp = part + ((size_t)(c * NCH2 + ch) * NB + b) * 4;
    #pragma unroll
    for (int q = 0; q < 4; ++q)
        pp[q] = make_float4(acc[q * 4 + 0], acc[q * 4 + 1],
                            acc[q * 4 + 2], acc[q * 4 + 3]);
}

// stage1: sum 8 chunks -> part2[t][e]; t = ((c*NB+b)*4+q), e in [0,8)
__global__ __launch_bounds__(256) void k_reduce1(const float4* __restrict__ part,
                                                 float4* __restrict__ part2) {
    int t = blockIdx.x * 256 + threadIdx.x;   // [0, 10240)
    int e = blockIdx.y;                        // [0, 8)
    int q = t & 3;
    int b = (t >> 2) & 255;
    int c = t >> 10;
    float4 s = make_float4(0.f, 0.f, 0.f, 0.f);
    #pragma unroll
    for (int k = 0; k < 8; ++k) {
        float4 v = part[(((size_t)c * NCH2 + e * 8 + k) * NB + b) * 4 + q];
        s.x += v.x; s.y += v.y; s.z += v.z; s.w += v.w;
    }
    part2[(size_t)t * 8 + e] = s;
}

// stage2: sum 8 partials, squash, write vbuf[c][b][o] (or out[b][c][o] last)
__global__ __launch_bounds__(256) void k_reduce2(const float4* __restrict__ part2,
                                                 float4* __restrict__ vbuf,
                                                 float4* __restrict__ out,
                                                 int final_pass) {
    int t = blockIdx.x * 256 + threadIdx.x;   // [0, 10240)
    int q = t & 3;
    int b = (t >> 2) & 255;
    int c = t >> 10;
    float4 s = make_float4(0.f, 0.f, 0.f, 0.f);
    #pragma unroll
    for (int e = 0; e < 8; ++e) {
        float4 v = part2[(size_t)t * 8 + e];
        s.x += v.x; s.y += v.y; s.z += v.z; s.w += v.w;
    }
    float4 r;
    r.x = s.x * fabsf(s.x) / (1.0f + s.x * s.x);
    r.y = s.y * fabsf(s.y) / (1.0f + s.y * s.y);
    r.z = s.z * fabsf(s.z) / (1.0f + s.z * s.z);
    r.w = s.w * fabsf(s.w) / (1.0f + s.w * s.w);
    if (final_pass) {
        out[((size_t)b * NC + c) * 4 + q] = r;
    } else {
        vbuf[t] = r;
    }
}

// bbuf[r,c] += (1/B) sum_b sum_o (sum_i W[r,c,o,i] x[b,r,i]) v[c,b,o]
// (round-6 verbatim: proven fast and correct)
template <int NCH, int RCHW>
__global__ __launch_bounds__(256, 4) void k_agree(const float* __restrict__ xT,
                                                  const float* __restrict__ W,
                                                  const float* __restrict__ vbuf,
                                                  float* __restrict__ bbuf) {
    const int ch2  = blockIdx.x;
    const int c    = blockIdx.y;
    const int tid  = threadIdx.x;
    const int wave = tid >> 6, lane = tid & 63;
    const int rs = wave >> 1, bh = wave & 1;

    __shared__ __align__(16) float Wl[2 * RCHW * 128];
    __shared__ __align__(16) float plds[2 * RCHW][2][64];

    for (int idx = tid; idx < 2 * RCHW * 32; idx += 256) {
        int rr = idx >> 5, j = idx & 31;
        reinterpret_cast<float4*>(Wl)[idx] =
            *(reinterpret_cast<const float4*>(
                  W + ((size_t)(ch2 * 2 * RCHW + rr) * NC + c) * 128) + j);
    }
    __syncthreads();

    const int b0 = bh * 128 + lane;
    float4 v0[4], v1[4];
    {
        const float4* vp0 = reinterpret_cast<const float4*>(
            vbuf + ((size_t)c * NB + b0) * NO);
        const float4* vp1 = reinterpret_cast<const float4*>(
            vbuf + ((size_t)c * NB + b0 + 64) * NO);
        #pragma unroll
        for (int q = 0; q < 4; ++q) { v0[q] = vp0[q]; v1[q] = vp1[q]; }
    }

    const float* xb = xT + (((size_t)(ch2 * 2 + rs) * RCHW) * NB + b0) * NI;

    #pragma unroll
    for (int rr = 0; rr < RCHW; ++rr) {
        const float4* xp = reinterpret_cast<const float4*>(xb + (size_t)rr * NB * NI);
        float4 xa0 = xp[0],   xa1 = xp[1];
        float4 xb0 = xp[128], xb1 = xp[129];
        const float* wrow = &Wl[(rs * RCHW + rr) * 128];
        float p = 0.0f;
        #pragma unroll
        for (int o = 0; o < NO; ++o) {
            float4 w0 = *reinterpret_cast<const float4*>(wrow + o * 8);
            float4 w1 = *reinterpret_cast<const float4*>(wrow + o * 8 + 4);
            float d0 = w0.x*xa0.x + w0.y*xa0.y + w0.z*xa0.z + w0.w*xa0.w
                     + w1.x*xa1.x + w1.y*xa1.y + w1.z*xa1.z + w1.w*xa1.w;
            float d1 = w0.x*xb0.x + w0.y*xb0.y + w0.z*xb0.z + w0.w*xb0.w
                     + w1.x*xb1.x + w1.y*xb1.y + w1.z*xb1.z + w1.w*xb1.w;
            const float* vf0 = reinterpret_cast<const float*>(&v0[o >> 2]);
            const float* vf1 = reinterpret_cast<const float*>(&v1[o >> 2]);
            p += d0 * vf0[o & 3] + d1 * vf1[o & 3];
        }
        plds[rs * RCHW + rr][bh][lane] = p;
    }
    __syncthreads();

    for (int r = wave; r < 2 * RCHW; r += 4) {
        float s = plds[r][0][lane] + plds[r][1][lane];
        s += __shfl_xor(s, 1);
        s += __shfl_xor(s, 2);
        s += __shfl_xor(s, 4);
        s += __shfl_xor(s, 8);
        s += __shfl_xor(s, 16);
        s += __shfl_xor(s, 32);
        if (lane == 0)
            bbuf[((size_t)ch2 * 2 * RCHW + r) * NC + c] += s * (1.0f / NB);
    }
}

// softmax over r (axis 0) per column c
__global__ __launch_bounds__(256) void k_softmax(const float* __restrict__ bbuf,
                                                 float* __restrict__ cbuf) {
    const int c   = blockIdx.x;
    const int tid = threadIdx.x;
    __shared__ float sred[4];
    __shared__ float sred2[4];
    int wave = tid >> 6, lane = tid & 63;

    float m = -1e30f;
    for (int r = tid; r < NR; r += 256) m = fmaxf(m, bbuf[r * NC + c]);
    #pragma unroll
    for (int off = 1; off < 64; off <<= 1) m = fmaxf(m, __shfl_xor(m, off));
    if (lane == 0) sred[wave] = m;
    __syncthreads();
    m = fmaxf(fmaxf(sred[0], sred[1]), fmaxf(sred[2], sred[3]));

    float s = 0.0f;
    for (int r = tid; r < NR; r += 256) {
        float e = expf(bbuf[r * NC + c] - m);
        cbuf[r * NC + c] = e;
        s += e;
    }
    #pragma unroll
    for (int off = 1; off < 64; off <<= 1) s += __shfl_xor(s, off);
    if (lane == 0) sred2[wave] = s;
    __syncthreads();
    s = sred2[0] + sred2[1] + sred2[2] + sred2[3];
    float inv = 1.0f / s;
    for (int r = tid; r < NR; r += 256) cbuf[r * NC + c] *= inv;
}

extern "C" void kernel_launch(void* const* d_in, const int* in_sizes, int n_in,
                              void* d_out, int out_size, void* d_ws, size_t ws_size,
                              hipStream_t stream) {
    const float* x = (const float*)d_in[0];   // [256,1152,8]
    const float* W = (const float*)d_in[1];   // [1152,10,16,8]
    float4* out = (float4*)d_out;             // [256,10,16,1]

    // Workspace: 21.49 MB, the exact footprint proven to fit in rounds 4/6.
    float4* part  = (float4*)d_ws;                       // 10*64*256*4 f4 = 10.49 MB
    float4* part2 = part + (size_t)NC * NCH2 * NB * 4;   // 10240*8 f4    =  1.31 MB
    float*  xT    = (float*)(part2 + (size_t)10240 * 8); // 2,359,296 f   =  9.44 MB
    float*  bbuf  = xT + (size_t)NR * NB * NI;           // 11,520 f
    float*  cbuf  = bbuf + (size_t)NR * NC;              // 11,520 f
    float*  vbuf  = cbuf + (size_t)NR * NC;              // 40,960 f

    k_init<<<(NR * NC + 255) / 256, 256, 0, stream>>>(bbuf, cbuf);
    {
        dim3 gt(NR / 128, NB / 8);
        k_transpose<<<gt, 256, 0, stream>>>(x, xT);
    }

    dim3 ghot(NCH2, NC);   // (64,10): c-blocks sharing x are 64 apart -> same XCD
    dim3 gr1(40, 8);

    for (int it = 0; it < 3; ++it) {
        k_partial<<<ghot, 256, 0, stream>>>(xT, W, cbuf, part);
        k_reduce1<<<gr1, 256, 0, stream>>>(part, part2);
        k_reduce2<<<40, 256, 0, stream>>>(part2, (float4*)vbuf, out, it == 2 ? 1 : 0);
        if (it < 2) {
            k_agree<NCH2, 9><<<ghot, 256, 0, stream>>>(xT, W, vbuf, bbuf);
            k_softmax<<<NC, 256, 0, stream>>>(bbuf, cbuf);
        }
    }
}

// Round 8
// 124.981 us; speedup vs baseline: 6.8358x; 1.2941x over previous
//
#include <hip/hip_runtime.h>
#include <math.h>

namespace {
constexpr int NB = 256;    // batch
constexpr int NR = 1152;   // routes
constexpr int NC = 10;     // output capsules
constexpr int NO = 16;     // output dim
constexpr int NI = 8;      // input dim
constexpr int K1 = NR * NI;        // 9216  (GEMM1 K, GEMM2 M)
constexpr int NN = NC * NO;        // 160   (N of both GEMMs)
constexpr int KS1 = 16;            // GEMM1 split-K slices
constexpr int KC1 = K1 / KS1;      // 576 per slice -> 18 mfma steps
}

using s16x8 = __attribute__((ext_vector_type(8))) short;
using f32x4 = __attribute__((ext_vector_type(4))) float;

__device__ __forceinline__ ushort f2bf(float f) {
    uint u = __float_as_uint(f);
    uint r = (u + 0x7FFFu + ((u >> 16) & 1u)) >> 16;
    return (ushort)r;
}

// b = 0, c = 1/R
__global__ __launch_bounds__(256) void k_init(float* __restrict__ bbuf,
                                              float* __restrict__ cbuf) {
    int i = blockIdx.x * 256 + threadIdx.x;
    if (i < NR * NC) { bbuf[i] = 0.0f; cbuf[i] = 1.0f / NR; }
}

// xbf[b][k] = bf16(x[b][k])   (x is [256][9216] contiguous)
__global__ __launch_bounds__(256) void k_xbf(const float* __restrict__ x,
                                             ushort* __restrict__ xbf) {
    size_t i8 = ((size_t)blockIdx.x * 256 + threadIdx.x) * 8;
    float4 v0 = *reinterpret_cast<const float4*>(x + i8);
    float4 v1 = *reinterpret_cast<const float4*>(x + i8 + 4);
    ushort o[8] = { f2bf(v0.x), f2bf(v0.y), f2bf(v0.z), f2bf(v0.w),
                    f2bf(v1.x), f2bf(v1.y), f2bf(v1.z), f2bf(v1.w) };
    *reinterpret_cast<uint4*>(xbf + i8) = *reinterpret_cast<uint4*>(o);
}

// xTbf[k][b] = bf16(x[b][k])  (LDS-staged transpose, 32 k-rows per block)
__global__ __launch_bounds__(256) void k_xT(const float* __restrict__ x,
                                            ushort* __restrict__ xTbf) {
    __shared__ __align__(16) ushort T[32][264];   // 528B rows (16B-divisible)
    const int k0 = blockIdx.x * 32;
    #pragma unroll
    for (int j = 0; j < 8; ++j) {
        int f  = j * 256 + threadIdx.x;   // [0,2048)
        int b  = f >> 3;
        int i4 = f & 7;
        float4 v = *reinterpret_cast<const float4*>(x + (size_t)b * K1 + k0 + i4 * 4);
        T[i4 * 4 + 0][b] = f2bf(v.x);
        T[i4 * 4 + 1][b] = f2bf(v.y);
        T[i4 * 4 + 2][b] = f2bf(v.z);
        T[i4 * 4 + 3][b] = f2bf(v.w);
    }
    __syncthreads();
    #pragma unroll
    for (int j = 0; j < 4; ++j) {
        int g   = j * 256 + threadIdx.x;  // [0,1024)
        int row = g >> 5;
        int q8  = g & 31;
        *reinterpret_cast<uint4*>(xTbf + (size_t)(k0 + row) * NB + q8 * 8) =
            *reinterpret_cast<const uint4*>(&T[row][q8 * 8]);
    }
}

// BcT[(c*16+o)][r*8+i] = bf16( cbuf[r,c] * W[r,c,o,i] )
__global__ __launch_bounds__(256) void k_bct(const float* __restrict__ W,
                                             const float* __restrict__ cbuf,
                                             ushort* __restrict__ BcT) {
    int t = blockIdx.x * 256 + threadIdx.x;   // [0, 184320) = (r*10+c)*16+o
    int o  = t & 15;
    int rc = t >> 4;                          // r*10+c
    int c  = rc % 10;
    int r  = rc / 10;
    float cr = cbuf[rc];
    float4 v0 = *reinterpret_cast<const float4*>(W + (size_t)t * 8);
    float4 v1 = *reinterpret_cast<const float4*>(W + (size_t)t * 8 + 4);
    ushort ob[8] = { f2bf(v0.x * cr), f2bf(v0.y * cr), f2bf(v0.z * cr), f2bf(v0.w * cr),
                     f2bf(v1.x * cr), f2bf(v1.y * cr), f2bf(v1.z * cr), f2bf(v1.w * cr) };
    *reinterpret_cast<uint4*>(BcT + (size_t)(c * NO + o) * K1 + r * 8) =
        *reinterpret_cast<uint4*>(ob);
}

// GEMM1: spart[ks][b][co] += x[b][K-slice] . Bc[K-slice][co]
// 1 wave/block; grid (16 mt, 10 nt, 16 ks); 18 mfma of 16x16x32.
__global__ __launch_bounds__(64) void k_gemm1(const ushort* __restrict__ xbf,
                                              const ushort* __restrict__ BcT,
                                              float* __restrict__ spart) {
    const int l  = threadIdx.x;
    const int m0 = blockIdx.x * 16;
    const int n0 = blockIdx.y * 16;
    const int k0 = blockIdx.z * KC1;
    const ushort* ap = xbf + (size_t)(m0 + (l & 15)) * K1 + k0 + 8 * (l >> 4);
    const ushort* bp = BcT + (size_t)(n0 + (l & 15)) * K1 + k0 + 8 * (l >> 4);
    f32x4 acc = {0.f, 0.f, 0.f, 0.f};
    #pragma unroll
    for (int kk = 0; kk < KC1 / 32; ++kk) {
        s16x8 a = *reinterpret_cast<const s16x8*>(ap + kk * 32);
        s16x8 b = *reinterpret_cast<const s16x8*>(bp + kk * 32);
        acc = __builtin_amdgcn_mfma_f32_16x16x32_bf16(a, b, acc, 0, 0, 0);
    }
    float* sp = spart + (size_t)blockIdx.z * (NB * NN)
              + (size_t)(m0 + 4 * (l >> 4)) * NN + n0 + (l & 15);
    #pragma unroll
    for (int q = 0; q < 4; ++q) sp[(size_t)q * NN] = acc[q];
}

// sum split-K, squash; write VT[co][b] bf16 (or out[b][co] fp32 on final pass)
__global__ __launch_bounds__(256) void k_sq(const float* __restrict__ spart,
                                            ushort* __restrict__ VT,
                                            float* __restrict__ out,
                                            int final_pass) {
    int f = blockIdx.x * 256 + threadIdx.x;   // [0,40960) = b*160+co
    float s = 0.0f;
    #pragma unroll
    for (int ks = 0; ks < KS1; ++ks) s += spart[(size_t)ks * (NB * NN) + f];
    float v = s * fabsf(s) / (1.0f + s * s);
    if (final_pass) {
        out[f] = v;
    } else {
        int b  = f / NN;
        int co = f % NN;
        VT[(size_t)co * NB + b] = f2bf(v);
    }
}

// GEMM2: PT[co][ri] = sum_b xT[ri][b] * v[b][co]
// 1 wave/block; grid (576 mt, 10 nt); K=256 -> 8 mfma. D stored transposed
// (lane writes 4 consecutive m -> one float4 per lane).
__global__ __launch_bounds__(64) void k_gemm2(const ushort* __restrict__ xTbf,
                                              const ushort* __restrict__ VT,
                                              float* __restrict__ PT) {
    const int l  = threadIdx.x;
    const int m0 = blockIdx.x * 16;
    const int n0 = blockIdx.y * 16;
    const ushort* ap = xTbf + (size_t)(m0 + (l & 15)) * NB + 8 * (l >> 4);
    const ushort* bp = VT   + (size_t)(n0 + (l & 15)) * NB + 8 * (l >> 4);
    f32x4 acc = {0.f, 0.f, 0.f, 0.f};
    #pragma unroll
    for (int kk = 0; kk < NB / 32; ++kk) {
        s16x8 a = *reinterpret_cast<const s16x8*>(ap + kk * 32);
        s16x8 b = *reinterpret_cast<const s16x8*>(bp + kk * 32);
        acc = __builtin_amdgcn_mfma_f32_16x16x32_bf16(a, b, acc, 0, 0, 0);
    }
    *reinterpret_cast<float4*>(PT + (size_t)(n0 + (l & 15)) * K1 + m0 + 4 * (l >> 4)) =
        make_float4(acc[0], acc[1], acc[2], acc[3]);
}

// bbuf[r,c] += (1/B) * sum_{o,i} W[r,c,o,i] * PT[c*16+o][r*8+i]
__global__ __launch_bounds__(128) void k_adot(const float* __restrict__ PT,
                                              const float* __restrict__ W,
                                              float* __restrict__ bbuf) {
    int t = blockIdx.x * 128 + threadIdx.x;   // [0,11520) = r*10+c
    int c = t % 10;
    int r = t / 10;
    const float4* wp = reinterpret_cast<const float4*>(W + (size_t)t * 128);
    float s = 0.0f;
    #pragma unroll
    for (int o = 0; o < NO; ++o) {
        float4 w0 = wp[o * 2];
        float4 w1 = wp[o * 2 + 1];
        const float4* pp = reinterpret_cast<const float4*>(
            PT + (size_t)(c * NO + o) * K1 + r * 8);
        float4 p0 = pp[0];
        float4 p1 = pp[1];
        s += w0.x * p0.x + w0.y * p0.y + w0.z * p0.z + w0.w * p0.w
           + w1.x * p1.x + w1.y * p1.y + w1.z * p1.z + w1.w * p1.w;
    }
    bbuf[t] += s * (1.0f / NB);
}

// softmax over r (axis 0) per column c
__global__ __launch_bounds__(256) void k_softmax(const float* __restrict__ bbuf,
                                                 float* __restrict__ cbuf) {
    const int c   = blockIdx.x;
    const int tid = threadIdx.x;
    __shared__ float sred[4];
    __shared__ float sred2[4];
    int wave = tid >> 6, lane = tid & 63;

    float m = -1e30f;
    for (int r = tid; r < NR; r += 256) m = fmaxf(m, bbuf[r * NC + c]);
    #pragma unroll
    for (int off = 1; off < 64; off <<= 1) m = fmaxf(m, __shfl_xor(m, off));
    if (lane == 0) sred[wave] = m;
    __syncthreads();
    m = fmaxf(fmaxf(sred[0], sred[1]), fmaxf(sred[2], sred[3]));

    float s = 0.0f;
    for (int r = tid; r < NR; r += 256) {
        float e = expf(bbuf[r * NC + c] - m);
        cbuf[r * NC + c] = e;
        s += e;
    }
    #pragma unroll
    for (int off = 1; off < 64; off <<= 1) s += __shfl_xor(s, off);
    if (lane == 0) sred2[wave] = s;
    __syncthreads();
    s = sred2[0] + sred2[1] + sred2[2] + sred2[3];
    float inv = 1.0f / s;
    for (int r = tid; r < NR; r += 256) cbuf[r * NC + c] *= inv;
}

extern "C" void kernel_launch(void* const* d_in, const int* in_sizes, int n_in,
                              void* d_out, int out_size, void* d_ws, size_t ws_size,
                              hipStream_t stream) {
    const float* x = (const float*)d_in[0];   // [256,1152,8] = [256][9216]
    const float* W = (const float*)d_in[1];   // [1152,10,16,8]
    float* out = (float*)d_out;               // [256,10,16,1] = [256][160]

    // Workspace layout (21.08 MB total, < proven-fit 21.49 MB):
    float*  spart = (float*)d_ws;                        // 16*40960 f   = 2.62 MB
    float*  PT    = spart + (size_t)KS1 * NB * NN;       // 160*9216 f   = 5.90 MB
    float*  bbuf  = PT + (size_t)NN * K1;                // 11520 f
    float*  cbuf  = bbuf + NR * NC;                      // 11520 f
    ushort* xbf   = (ushort*)(cbuf + NR * NC);           // 256*9216 u16 = 4.72 MB
    ushort* xTbf  = xbf + (size_t)NB * K1;               // 9216*256 u16 = 4.72 MB
    ushort* BcT   = xTbf + (size_t)K1 * NB;              // 160*9216 u16 = 2.95 MB
    ushort* VT    = BcT + (size_t)NN * K1;               // 160*256  u16 = 80 KB

    k_init<<<(NR * NC + 255) / 256, 256, 0, stream>>>(bbuf, cbuf);
    k_xbf<<<(NB * K1) / (256 * 8), 256, 0, stream>>>(x, xbf);      // 1152 blocks
    k_xT<<<K1 / 32, 256, 0, stream>>>(x, xTbf);                    // 288 blocks

    dim3 g1(NB / 16, NN / 16, KS1);   // (16,10,16)
    dim3 g2(K1 / 16, NN / 16);        // (576,10)

    for (int it = 0; it < 3; ++it) {
        k_bct<<<(NR * NC * NO) / 256, 256, 0, stream>>>(W, cbuf, BcT);  // 720 blocks
        k_gemm1<<<g1, 64, 0, stream>>>(xbf, BcT, spart);
        k_sq<<<(NB * NN) / 256, 256, 0, stream>>>(spart, VT, out, it == 2 ? 1 : 0);
        if (it < 2) {
            k_gemm2<<<g2, 64, 0, stream>>>(xTbf, VT, PT);
            k_adot<<<(NR * NC) / 128, 128, 0, stream>>>(PT, W, bbuf);   // 90 blocks
            k_softmax<<<NC, 256, 0, stream>>>(bbuf, cbuf);
        }
    }
}

// Round 9
// 120.511 us; speedup vs baseline: 7.0894x; 1.0371x over previous
//
#include <hip/hip_runtime.h>
#include <math.h>

namespace {
constexpr int NB = 256;    // batch
constexpr int NR = 1152;   // routes
constexpr int NC = 10;     // output capsules
constexpr int NO = 16;     // output dim
constexpr int NI = 8;      // input dim
constexpr int K1 = NR * NI;   // 9216 (GEMM1 K, GEMM2 M)
constexpr int NN = NC * NO;   // 160
}

using s16x8 = __attribute__((ext_vector_type(8))) short;
using f32x4 = __attribute__((ext_vector_type(4))) float;

__device__ __forceinline__ ushort f2bf(float f) {
    uint u = __float_as_uint(f);
    uint r = (u + 0x7FFFu + ((u >> 16) & 1u)) >> 16;
    return (ushort)r;
}

// prep: xbf[b][k], xTbf[k][b] (one x read, LDS transpose), BcT0 = bf16(W/NR)
__global__ __launch_bounds__(256) void k_prep(const float* __restrict__ x,
                                              const float* __restrict__ W,
                                              ushort* __restrict__ xbf,
                                              ushort* __restrict__ xTbf,
                                              ushort* __restrict__ BcT) {
    __shared__ __align__(16) ushort T[32][264];
    const int k0 = blockIdx.x * 32;          // 288 blocks cover K1
    #pragma unroll
    for (int j = 0; j < 8; ++j) {
        int f  = j * 256 + threadIdx.x;      // [0,2048)
        int b  = f >> 3;
        int i4 = f & 7;
        float4 v = *reinterpret_cast<const float4*>(x + (size_t)b * K1 + k0 + i4 * 4);
        ushort bv[4] = { f2bf(v.x), f2bf(v.y), f2bf(v.z), f2bf(v.w) };
        T[i4 * 4 + 0][b] = bv[0];
        T[i4 * 4 + 1][b] = bv[1];
        T[i4 * 4 + 2][b] = bv[2];
        T[i4 * 4 + 3][b] = bv[3];
        *reinterpret_cast<ushort4*>(xbf + (size_t)b * K1 + k0 + i4 * 4) =
            make_ushort4(bv[0], bv[1], bv[2], bv[3]);
    }
    __syncthreads();
    #pragma unroll
    for (int j = 0; j < 4; ++j) {
        int g   = j * 256 + threadIdx.x;     // [0,1024)
        int row = g >> 5;
        int q8  = g & 31;
        *reinterpret_cast<uint4*>(xTbf + (size_t)(k0 + row) * NB + q8 * 8) =
            *reinterpret_cast<const uint4*>(&T[row][q8 * 8]);
    }
    // BcT0: 184320 (r,c,o) rows of 8, grid-stride
    const float cr0 = 1.0f / NR;
    for (size_t e = (size_t)blockIdx.x * 256 + threadIdx.x; e < (size_t)NR * NC * NO;
         e += (size_t)288 * 256) {
        int o  = (int)(e & 15);
        int rc = (int)(e >> 4);
        int c  = rc % NC;
        int r  = rc / NC;
        float4 v0 = *reinterpret_cast<const float4*>(W + e * 8);
        float4 v1 = *reinterpret_cast<const float4*>(W + e * 8 + 4);
        ushort ob[8] = { f2bf(v0.x * cr0), f2bf(v0.y * cr0), f2bf(v0.z * cr0), f2bf(v0.w * cr0),
                         f2bf(v1.x * cr0), f2bf(v1.y * cr0), f2bf(v1.z * cr0), f2bf(v1.w * cr0) };
        *reinterpret_cast<uint4*>(BcT + (size_t)(c * NO + o) * K1 + r * 8) =
            *reinterpret_cast<uint4*>(ob);
    }
}

// GEMM1 + split-K-in-block + squash. Grid (16,10), 4 waves; wave w: K-slice w.
// Writes VT[co][b] bf16, or out[b][co] fp32 on final pass.
__global__ __launch_bounds__(256) void k_g1sq(const ushort* __restrict__ xbf,
                                              const ushort* __restrict__ BcT,
                                              ushort* __restrict__ VT,
                                              float* __restrict__ out,
                                              int final_pass) {
    const int m0 = blockIdx.x * 16;
    const int n0 = blockIdx.y * 16;
    const int w  = threadIdx.x >> 6, l = threadIdx.x & 63;
    const int k0 = w * (K1 / 4);

    const ushort* ap = xbf + (size_t)(m0 + (l & 15)) * K1 + k0 + 8 * (l >> 4);
    const ushort* bp = BcT + (size_t)(n0 + (l & 15)) * K1 + k0 + 8 * (l >> 4);
    f32x4 acc = {0.f, 0.f, 0.f, 0.f};
    #pragma unroll 4
    for (int kk = 0; kk < K1 / 4 / 32; ++kk) {   // 72
        s16x8 a = *reinterpret_cast<const s16x8*>(ap + kk * 32);
        s16x8 b = *reinterpret_cast<const s16x8*>(bp + kk * 32);
        acc = __builtin_amdgcn_mfma_f32_16x16x32_bf16(a, b, acc, 0, 0, 0);
    }

    __shared__ float red[4][16][16];
    #pragma unroll
    for (int q = 0; q < 4; ++q) red[w][4 * (l >> 4) + q][l & 15] = acc[q];
    __syncthreads();

    const int row = threadIdx.x >> 4, col = threadIdx.x & 15;
    float s = red[0][row][col] + red[1][row][col] + red[2][row][col] + red[3][row][col];
    float v = s * fabsf(s) / (1.0f + s * s);
    if (final_pass) {
        out[(size_t)(m0 + row) * NN + n0 + col] = v;
    } else {
        VT[(size_t)(n0 + col) * NB + m0 + row] = f2bf(v);
    }
}

// GEMM2 (P-tile in regs) + W-contraction -> bbuf[r,c] directly. PT never stored.
// Grid (144, 10), 4 waves; wave m-tile = 16 ri (2 r). Each (r,c) written once.
__global__ __launch_bounds__(256) void k_g2adot(const ushort* __restrict__ xTbf,
                                                const ushort* __restrict__ VT,
                                                const float* __restrict__ W,
                                                float* __restrict__ bbuf,
                                                int accum) {
    const int c  = blockIdx.y;
    const int w  = threadIdx.x >> 6, l = threadIdx.x & 63;
    const int m0 = blockIdx.x * 64 + w * 16;
    const int n0 = c * 16;

    const ushort* ap = xTbf + (size_t)(m0 + (l & 15)) * NB + 8 * (l >> 4);
    const ushort* bp = VT   + (size_t)(n0 + (l & 15)) * NB + 8 * (l >> 4);
    f32x4 acc = {0.f, 0.f, 0.f, 0.f};
    #pragma unroll
    for (int kk = 0; kk < NB / 32; ++kk) {       // 8
        s16x8 a = *reinterpret_cast<const s16x8*>(ap + kk * 32);
        s16x8 b = *reinterpret_cast<const s16x8*>(bp + kk * 32);
        acc = __builtin_amdgcn_mfma_f32_16x16x32_bf16(a, b, acc, 0, 0, 0);
    }

    // lane l: D rows ri = m0+4h+q (h=l>>4), col o = l&15.
    // ri block h: r = (m0>>3)+(h>=2), i0 = (4h)&7 -> one float4 of W covers q=0..3.
    const int h  = l >> 4, o = l & 15;
    const int r  = (m0 >> 3) + (h >> 1);
    const int i0 = (4 * h) & 7;
    const float4 w4 = *reinterpret_cast<const float4*>(
        W + (((size_t)r * NC + c) * NO + o) * NI + i0);
    float s = acc[0] * w4.x + acc[1] * w4.y + acc[2] * w4.z + acc[3] * w4.w;
    s += __shfl_xor(s, 1);
    s += __shfl_xor(s, 2);
    s += __shfl_xor(s, 4);
    s += __shfl_xor(s, 8);    // sum over o within h-group
    s += __shfl_xor(s, 16);   // combine i-halves (h0+h1, h2+h3)
    if (l == 0 || l == 32) {
        int rr = (m0 >> 3) + (l >> 5);
        float val = s * (1.0f / NB);
        if (accum) bbuf[(size_t)rr * NC + c] += val;
        else       bbuf[(size_t)rr * NC + c] = val;
    }
}

// softmax over r for capsule c (redundant per 8 blocks) + write BcT r-slice.
// Grid 80 = 10 c x 8 r-slices of 144.
__global__ __launch_bounds__(256) void k_smax_bct(const float* __restrict__ bbuf,
                                                  const float* __restrict__ W,
                                                  ushort* __restrict__ BcT) {
    const int c  = blockIdx.x >> 3;
    const int rs = blockIdx.x & 7;
    const int tid = threadIdx.x;
    __shared__ float sred[4];
    __shared__ float sred2[4];
    const int wv = tid >> 6, ln = tid & 63;

    float m = -1e30f;
    for (int r = tid; r < NR; r += 256) m = fmaxf(m, bbuf[r * NC + c]);
    #pragma unroll
    for (int off = 1; off < 64; off <<= 1) m = fmaxf(m, __shfl_xor(m, off));
    if (ln == 0) sred[wv] = m;
    __syncthreads();
    m = fmaxf(fmaxf(sred[0], sred[1]), fmaxf(sred[2], sred[3]));

    float s = 0.0f;
    for (int r = tid; r < NR; r += 256) s += expf(bbuf[r * NC + c] - m);
    #pragma unroll
    for (int off = 1; off < 64; off <<= 1) s += __shfl_xor(s, off);
    if (ln == 0) sred2[wv] = s;
    __syncthreads();
    s = sred2[0] + sred2[1] + sred2[2] + sred2[3];
    const float inv = 1.0f / s;

    for (int e = tid; e < NO * 144; e += 256) {   // 2304 (o, rr) cells
        int o  = e / 144;
        int rr = e - o * 144;
        int r  = rs * 144 + rr;
        float cr = expf(bbuf[r * NC + c] - m) * inv;
        const float4* wp = reinterpret_cast<const float4*>(
            W + (((size_t)r * NC + c) * NO + o) * NI);
        float4 v0 = wp[0];
        float4 v1 = wp[1];
        ushort ob[8] = { f2bf(v0.x * cr), f2bf(v0.y * cr), f2bf(v0.z * cr), f2bf(v0.w * cr),
                         f2bf(v1.x * cr), f2bf(v1.y * cr), f2bf(v1.z * cr), f2bf(v1.w * cr) };
        *reinterpret_cast<uint4*>(BcT + (size_t)(c * NO + o) * K1 + r * 8) =
            *reinterpret_cast<uint4*>(ob);
    }
}

extern "C" void kernel_launch(void* const* d_in, const int* in_sizes, int n_in,
                              void* d_out, int out_size, void* d_ws, size_t ws_size,
                              hipStream_t stream) {
    const float* x = (const float*)d_in[0];   // [256][9216]
    const float* W = (const float*)d_in[1];   // [1152,10,16,8]
    float* out = (float*)d_out;               // [256][160]

    // ws: bbuf(f32) | xbf | xTbf | BcT | VT  (~12.6 MB)
    float*  bbuf = (float*)d_ws;                          // 11520 f
    ushort* xbf  = (ushort*)(bbuf + (size_t)NR * NC);     // 256*9216
    ushort* xTbf = xbf + (size_t)NB * K1;                 // 9216*256
    ushort* BcT  = xTbf + (size_t)K1 * NB;                // 160*9216
    ushort* VT   = BcT + (size_t)NN * K1;                 // 160*256

    k_prep<<<K1 / 32, 256, 0, stream>>>(x, W, xbf, xTbf, BcT);   // 288 blocks

    dim3 g1(NB / 16, NC);      // (16,10)
    dim3 g2(K1 / 64, NC);      // (144,10)

    for (int it = 0; it < 3; ++it) {
        k_g1sq<<<g1, 256, 0, stream>>>(xbf, BcT, VT, out, it == 2 ? 1 : 0);
        if (it < 2) {
            k_g2adot<<<g2, 256, 0, stream>>>(xTbf, VT, W, bbuf, it == 0 ? 0 : 1);
            k_smax_bct<<<80, 256, 0, stream>>>(bbuf, W, BcT);
        }
    }
}